// Round 10
// baseline (209.085 us; speedup 1.0000x reference)
//
#include <hip/hip_runtime.h>

// AttentionBase: B=2, N=2048, D=1024, H=16, hd=64. fp32 in/out, bf16 MFMA inside.
#define D_MODEL 1024
#define N_TOK   2048
#define NHEAD   16
#define HDIM    64
#define BATCH   2
#define M_TOT   (BATCH*N_TOK)   // 4096 tokens

typedef unsigned short u16;
typedef __bf16 bf16x8 __attribute__((ext_vector_type(8)));
typedef float  f32x4  __attribute__((ext_vector_type(4)));

// attention scale folded into W_q: D^-0.5 * log2(e), so P = exp2(S) directly
#define QSCALE 0.04508422002777439f

__device__ __forceinline__ u16 f2bf(float f) {
  union { float f; unsigned u; } v; v.f = f;
  unsigned r = v.u + 0x7fffu + ((v.u >> 16) & 1u);   // RNE
  return (u16)(r >> 16);
}

__device__ __forceinline__ float bf2f(u16 u) {
  union { unsigned u; float f; } v; v.u = ((unsigned)u) << 16; return v.f;
}

__device__ __forceinline__ unsigned pk2bf(float a, float b) {
#if __has_builtin(__builtin_amdgcn_cvt_pk_bf16_f32)
  typedef __bf16 bf16x2_t __attribute__((ext_vector_type(2)));
  bf16x2_t r = __builtin_amdgcn_cvt_pk_bf16_f32(a, b);
  union { bf16x2_t v; unsigned u; } c; c.v = r; return c.u;
#else
  return (unsigned)f2bf(a) | ((unsigned)f2bf(b) << 16);
#endif
}

// combine two packed bf16 pairs: out = pk((a.lo+b.lo)*inv, (a.hi+b.hi)*inv)
__device__ __forceinline__ unsigned comb2(unsigned a, unsigned b, float inv) {
  float x = (bf2f((u16)(a & 0xffff)) + bf2f((u16)(b & 0xffff))) * inv;
  float y = (bf2f((u16)(a >> 16))   + bf2f((u16)(b >> 16)))   * inv;
  return pk2bf(x, y);
}

__device__ __forceinline__ void gl2lds16(const void* g, void* l) {
  __builtin_amdgcn_global_load_lds(
      (__attribute__((address_space(1))) void*)g,
      (__attribute__((address_space(3))) void*)l, 16, 0, 0);
}

// ---------- fused prep: z<4 -> transpose+cast W[z]; z==4 -> cast x ----------
__global__ void prep_kernel(const float* __restrict__ x,
                            const float* __restrict__ s0, const float* __restrict__ s1,
                            const float* __restrict__ s2, const float* __restrict__ s3,
                            u16* __restrict__ xb,
                            u16* __restrict__ d0, u16* __restrict__ d1,
                            u16* __restrict__ d2, u16* __restrict__ d3) {
  const int t = threadIdx.y * 32 + threadIdx.x;
  if (blockIdx.z == 4) {
    // cast x: 1,048,576 float4 chunks; 1024 blocks x 256 thr x 4 iters
    int base = (blockIdx.y * 32 + blockIdx.x) * 256 + t;
#pragma unroll
    for (int r = 0; r < 4; ++r) {
      int i = base + r * 262144;
      float4 v = ((const float4*)x)[i];
      ushort4 o;
      o.x = f2bf(v.x); o.y = f2bf(v.y); o.z = f2bf(v.z); o.w = f2bf(v.w);
      ((ushort4*)xb)[i] = o;
    }
    return;
  }
  const float* src; u16* dst;
  switch (blockIdx.z) {
    case 0:  src = s0; dst = d0; break;
    case 1:  src = s1; dst = d1; break;
    case 2:  src = s2; dst = d2; break;
    default: src = s3; dst = d3; break;
  }
  float sc = (blockIdx.z == 0) ? QSCALE : 1.0f;
  __shared__ float tile[32][33];
  int xg = blockIdx.x * 32 + threadIdx.x;
  int ybase = blockIdx.y * 32;
#pragma unroll
  for (int r = 0; r < 4; ++r)
    tile[threadIdx.y + r*8][threadIdx.x] = src[(size_t)(ybase + threadIdx.y + r*8)*D_MODEL + xg];
  __syncthreads();
#pragma unroll
  for (int r = 0; r < 4; ++r)
    dst[(size_t)(blockIdx.x*32 + threadIdx.y + r*8)*D_MODEL + ybase + threadIdx.x] =
        f2bf(tile[threadIdx.x][threadIdx.y + r*8] * sc);
}

// ---------- 128x128 bf16 MFMA GEMM, dbuf LDS, coalesced [bh][n][64] epilogue -
// C tile is bounced through the 32 KB LDS pool (chunk-XOR swizzle) and stored
// as contiguous 16B chunks per (token, head) row — replaces r9's 64 scalar
// 2-byte global stores per thread (4x vector-mem transaction inflation).
__device__ __forceinline__ void gemm_body(const u16* __restrict__ A,
                                          const u16* __restrict__ Bt,
                                          u16* __restrict__ D) {
  __shared__ __attribute__((aligned(16))) u16 sm[16384];   // 32 KB pool
  const int t = threadIdx.x;
  const int lane = t & 63, w = t >> 6;
  const int wm = w >> 1, wn = w & 1;
  const int q4 = lane >> 4, l15 = lane & 15;
  const int m0 = blockIdx.y * 128, n0 = blockIdx.x * 128;

  const int c0 = t, c1 = 256 + t;
  const int r0 = c0 >> 2, g0 = (c0 & 3) ^ (r0 & 3);
  const int r1 = c1 >> 2, g1 = (c1 & 3) ^ (r1 & 3);

  f32x4 acc[4][4] = {};

  // buffers: A at sm + cur*4096, B at sm + 8192 + cur*4096 (u16 units)
  gl2lds16(A  + (size_t)(m0 + r0)*D_MODEL + g0*8, sm + c0*8);
  gl2lds16(Bt + (size_t)(n0 + r0)*D_MODEL + g0*8, sm + 8192 + c0*8);
  gl2lds16(A  + (size_t)(m0 + r1)*D_MODEL + g1*8, sm + c1*8);
  gl2lds16(Bt + (size_t)(n0 + r1)*D_MODEL + g1*8, sm + 8192 + c1*8);

  for (int it = 0; it < 32; ++it) {
    const int cur = it & 1;
    __syncthreads();
    if (it + 1 < 32) {
      const int kn = (it + 1) * 32;
      u16* dA = sm + (cur ^ 1) * 4096;
      u16* dB = sm + 8192 + (cur ^ 1) * 4096;
      gl2lds16(A  + (size_t)(m0 + r0)*D_MODEL + kn + g0*8, dA + c0*8);
      gl2lds16(Bt + (size_t)(n0 + r0)*D_MODEL + kn + g0*8, dB + c0*8);
      gl2lds16(A  + (size_t)(m0 + r1)*D_MODEL + kn + g1*8, dA + c1*8);
      gl2lds16(Bt + (size_t)(n0 + r1)*D_MODEL + kn + g1*8, dB + c1*8);
    }
    const u16* sA = sm + cur * 4096;
    const u16* sB = sm + 8192 + cur * 4096;
    bf16x8 af[4], bfr[4];
#pragma unroll
    for (int mi = 0; mi < 4; ++mi) {
      int r = wm*64 + mi*16 + l15;
      af[mi] = *(const bf16x8*)(sA + r*32 + ((q4 ^ (r & 3)) * 8));
    }
#pragma unroll
    for (int ni = 0; ni < 4; ++ni) {
      int r = wn*64 + ni*16 + l15;
      bfr[ni] = *(const bf16x8*)(sB + r*32 + ((q4 ^ (r & 3)) * 8));
    }
#pragma unroll
    for (int mi = 0; mi < 4; ++mi)
#pragma unroll
      for (int ni = 0; ni < 4; ++ni)
        acc[mi][ni] = __builtin_amdgcn_mfma_f32_16x16x32_bf16(af[mi], bfr[ni], acc[mi][ni], 0, 0, 0);
  }

  // ---- epilogue: LDS bounce -> coalesced 16B stores ----
  __syncthreads();   // all waves done reading K-loop buffers
#pragma unroll
  for (int mi = 0; mi < 4; ++mi)
#pragma unroll
    for (int ni = 0; ni < 4; ++ni) {
      const int row0 = wm*64 + mi*16 + q4*4;
      const int col  = wn*64 + ni*16 + l15;
      const int ch = col >> 3, c7 = col & 7;
#pragma unroll
      for (int r = 0; r < 4; ++r) {
        const int row = row0 + r;
        sm[row*128 + ((ch ^ (row & 15)) * 8) + c7] = f2bf(acc[mi][ni][r]);
      }
    }
  __syncthreads();
  {
    const int tokL = t & 127, h = t >> 7;           // one (token, head) row each
    const int tokG = m0 + tokL;
    const int b = tokG >> 11, n = tokG & (N_TOK-1);
    const int hg = (n0 >> 6) + h;
    u16* dst = D + (((size_t)(b*NHEAD + hg))*N_TOK + n)*HDIM;
#pragma unroll
    for (int ch = 0; ch < 8; ++ch) {
      uint4 v = *(const uint4*)(sm + tokL*128 + (((h*8 + ch) ^ (tokL & 15)) * 8));
      *(uint4*)(dst + ch*8) = v;
    }
  }
}

__global__ __launch_bounds__(256) void qkv_kernel(const u16* __restrict__ xb,
    const u16* __restrict__ wqt, const u16* __restrict__ wkt, const u16* __restrict__ wvt,
    u16* __restrict__ Q, u16* __restrict__ K, u16* __restrict__ V) {
  int z = blockIdx.z;
  const u16* B = (z == 0) ? wqt : (z == 1) ? wkt : wvt;
  u16* C = (z == 0) ? Q : (z == 1) ? K : V;
  gemm_body(xb, B, C);
}

// ---------- V transpose: [bh][n][64] -> [bh][64][n] (prep-verified pattern) --
__global__ void vtrans_kernel(const u16* __restrict__ V, u16* __restrict__ Vt) {
  __shared__ u16 tile[32][34];
  const int bh = blockIdx.z;
  const int n0 = blockIdx.x * 32, d0 = blockIdx.y * 32;
  const u16* src = V + ((size_t)bh*N_TOK + n0)*HDIM + d0;
  u16* dst = Vt + ((size_t)bh*HDIM + d0)*N_TOK + n0;
#pragma unroll
  for (int r = 0; r < 4; ++r)
    tile[threadIdx.y + r*8][threadIdx.x] =
        src[(size_t)(threadIdx.y + r*8)*HDIM + threadIdx.x];
  __syncthreads();
#pragma unroll
  for (int r = 0; r < 4; ++r)
    dst[(size_t)(threadIdx.y + r*8)*N_TOK + threadIdx.x] =
        tile[threadIdx.x][threadIdx.y + r*8];
}

// ---------- out GEMM fused with combine: A = (Op0+Op1)/l, 64x128 tile -------
// Op: [2][4096][1024] bf16 unnormalized partials; Lp: [2][32][2048] fp32 sums.
__global__ __launch_bounds__(256) void out_kernel(const u16* __restrict__ Op,
    const float* __restrict__ Lp, const u16* __restrict__ wot,
    float* __restrict__ out) {
  __shared__ __attribute__((aligned(16))) u16 lA[2][64*32];
  __shared__ __attribute__((aligned(16))) u16 lB[2][128*32];
  const int t = threadIdx.x;
  const int lane = t & 63, w = t >> 6;
  const int wm = w >> 1, wn = w & 1;
  const int q4 = lane >> 4, l15 = lane & 15;
  const int m0 = blockIdx.y * 64, n0 = blockIdx.x * 128;

  const int rA = t >> 2, gA = (t & 3) ^ (rA & 3);
  const int tok = m0 + rA;
  const int nA = tok & (N_TOK-1), bA = tok >> 11;
  const int c0 = t, c1 = 256 + t;
  const int r0 = c0 >> 2, g0 = (c0 & 3) ^ (r0 & 3);
  const int r1 = c1 >> 2, g1 = (c1 & 3) ^ (r1 & 3);

  f32x4 acc[2][4] = {};
  uint4 pa, pb;
  float l0, l1;

  // prologue (it = 0, head h = 0)
  {
    const size_t off = (size_t)tok*D_MODEL + gA*8;
    pa = *(const uint4*)(Op + off);
    pb = *(const uint4*)(Op + (size_t)(M_TOT*D_MODEL) + off);
    l0 = Lp[(size_t)(bA*NHEAD)*N_TOK + nA];
    l1 = Lp[(size_t)(32*N_TOK) + (size_t)(bA*NHEAD)*N_TOK + nA];
    gl2lds16(wot + (size_t)(n0 + r0)*D_MODEL + g0*8, &lB[0][c0*8]);
    gl2lds16(wot + (size_t)(n0 + r1)*D_MODEL + g1*8, &lB[0][c1*8]);
    float inv = 1.0f / (l0 + l1);
    uint4 o;
    o.x = comb2(pa.x, pb.x, inv); o.y = comb2(pa.y, pb.y, inv);
    o.z = comb2(pa.z, pb.z, inv); o.w = comb2(pa.w, pb.w, inv);
    *(uint4*)(&lA[0][t*8]) = o;
  }

  for (int it = 0; it < 32; ++it) {
    const int cur = it & 1;
    __syncthreads();
    const bool hasNext = (it + 1) < 32;
    if (hasNext) {
      const int kn = (it + 1) * 32;
      const int h2 = (it + 1) >> 1;
      const size_t off = (size_t)tok*D_MODEL + kn + gA*8;
      pa = *(const uint4*)(Op + off);
      pb = *(const uint4*)(Op + (size_t)(M_TOT*D_MODEL) + off);
      l0 = Lp[(size_t)(bA*NHEAD + h2)*N_TOK + nA];
      l1 = Lp[(size_t)(32*N_TOK) + (size_t)(bA*NHEAD + h2)*N_TOK + nA];
      u16* dB = &lB[cur ^ 1][0];
      gl2lds16(wot + (size_t)(n0 + r0)*D_MODEL + kn + g0*8, dB + c0*8);
      gl2lds16(wot + (size_t)(n0 + r1)*D_MODEL + kn + g1*8, dB + c1*8);
    }
    const u16* sA = &lA[cur][0]; const u16* sB = &lB[cur][0];
    bf16x8 af[2], bfr[4];
#pragma unroll
    for (int mi = 0; mi < 2; ++mi) {
      int r = wm*32 + mi*16 + l15;
      af[mi] = *(const bf16x8*)(sA + r*32 + ((q4 ^ (r & 3)) * 8));
    }
#pragma unroll
    for (int ni = 0; ni < 4; ++ni) {
      int r = wn*64 + ni*16 + l15;
      bfr[ni] = *(const bf16x8*)(sB + r*32 + ((q4 ^ (r & 3)) * 8));
    }
#pragma unroll
    for (int mi = 0; mi < 2; ++mi)
#pragma unroll
      for (int ni = 0; ni < 4; ++ni)
        acc[mi][ni] = __builtin_amdgcn_mfma_f32_16x16x32_bf16(af[mi], bfr[ni], acc[mi][ni], 0, 0, 0);
    if (hasNext) {
      float inv = 1.0f / (l0 + l1);
      uint4 o;
      o.x = comb2(pa.x, pb.x, inv); o.y = comb2(pa.y, pb.y, inv);
      o.z = comb2(pa.z, pb.z, inv); o.w = comb2(pa.w, pb.w, inv);
      *(uint4*)(&lA[cur ^ 1][t*8]) = o;
    }
  }

#pragma unroll
  for (int mi = 0; mi < 2; ++mi) {
#pragma unroll
    for (int ni = 0; ni < 4; ++ni) {
      const int tok0 = m0 + wm*32 + mi*16 + q4*4;
      const int col  = n0 + wn*64 + ni*16 + l15;
#pragma unroll
      for (int r = 0; r < 4; ++r)
        out[(size_t)(tok0 + r)*D_MODEL + col] = acc[mi][ni][r];
    }
  }
}

// ---------- flash attention, S^T form, 32 q/wave, kv-split x2, 32 KB LDS ----
// (unchanged from r9 — the 56 µs control)
__global__ __launch_bounds__(256, 4) void attn_kernel(const u16* __restrict__ Qg,
    const u16* __restrict__ Kg, const u16* __restrict__ Vtg,
    u16* __restrict__ Opart, float* __restrict__ Lpart) {
  __shared__ __attribute__((aligned(16))) u16 lds[16384];
  const int t = threadIdx.x;
  const int lane = t & 63, w = t >> 6;
  const int q4 = lane >> 4, l15 = lane & 15;
  const int bh = blockIdx.y;
  const int qb = blockIdx.x >> 1, sp = blockIdx.x & 1;
  const int qw0 = qb * 128 + w * 32;
  const size_t kvBase = (size_t)bh * (N_TOK * HDIM);
  u16* myP = lds + 8192 + w * 2048;

  const int ck0 = t, ck1 = 256 + t;
  const int kr0 = ck0 >> 3, kg0 = (ck0 & 7) ^ (kr0 & 7);
  const int kr1 = ck1 >> 3, kg1 = (ck1 & 7) ^ (kr1 & 7);

  bf16x8 qf[2][2];
#pragma unroll
  for (int ni = 0; ni < 2; ++ni)
#pragma unroll
    for (int kk = 0; kk < 2; ++kk)
      qf[ni][kk] = *(const bf16x8*)(Qg + kvBase +
                    (size_t)(qw0 + ni*16 + l15)*HDIM + kk*32 + q4*8);

  f32x4 accO[4][2] = {};
  float lsum[2] = {0.f, 0.f};

  const int kvStart = sp * 1024;
  for (int it = 0; it < 16; ++it) {
    const int kv0 = kvStart + it * 64;
    __syncthreads();
    gl2lds16(Kg  + kvBase + (size_t)(kv0 + kr0)*HDIM + kg0*8, lds + ck0*8);
    gl2lds16(Kg  + kvBase + (size_t)(kv0 + kr1)*HDIM + kg1*8, lds + ck1*8);
    gl2lds16(Vtg + kvBase + (size_t)kr0*N_TOK + kv0 + kg0*8,  lds + 4096 + ck0*8);
    gl2lds16(Vtg + kvBase + (size_t)kr1*N_TOK + kv0 + kg1*8,  lds + 4096 + ck1*8);
    __syncthreads();

#pragma unroll
    for (int mip = 0; mip < 4; ++mip) {
      const int kv = mip*16 + l15;
      f32x4 s[2] = {};
#pragma unroll
      for (int kk = 0; kk < 2; ++kk) {
        bf16x8 a = *(const bf16x8*)(lds + kv*64 + (((kk*4 + q4) ^ (l15 & 7)) * 8));
#pragma unroll
        for (int ni = 0; ni < 2; ++ni)
          s[ni] = __builtin_amdgcn_mfma_f32_16x16x32_bf16(a, qf[ni][kk], s[ni], 0, 0, 0);
      }
#pragma unroll
      for (int ni = 0; ni < 2; ++ni) {
        float p0 = __builtin_amdgcn_exp2f(s[ni][0]);
        float p1 = __builtin_amdgcn_exp2f(s[ni][1]);
        float p2 = __builtin_amdgcn_exp2f(s[ni][2]);
        float p3 = __builtin_amdgcn_exp2f(s[ni][3]);
        lsum[ni] += (p0 + p1) + (p2 + p3);
        uint2 u; u.x = pk2bf(p0, p1); u.y = pk2bf(p2, p3);
        const int qloc = ni*16 + l15;
        const int kv8 = mip*4 + q4;
        *(uint2*)(myP + qloc*64 + (((kv8 >> 1) ^ (qloc & 7)) * 8) + (kv8 & 1)*4) = u;
      }
    }

#pragma unroll
    for (int kk2 = 0; kk2 < 2; ++kk2) {
      bf16x8 bp[2];
#pragma unroll
      for (int ni = 0; ni < 2; ++ni)
        bp[ni] = *(const bf16x8*)(myP + (ni*16 + l15)*64 +
                                  (((kk2*4 + q4) ^ (l15 & 7)) * 8));
#pragma unroll
      for (int mi2 = 0; mi2 < 4; ++mi2) {
        const int d = mi2*16 + l15;
        bf16x8 av = *(const bf16x8*)(lds + 4096 + d*64 +
                                     (((kk2*4 + q4) ^ (d & 7)) * 8));
#pragma unroll
        for (int ni = 0; ni < 2; ++ni)
          accO[mi2][ni] = __builtin_amdgcn_mfma_f32_16x16x32_bf16(av, bp[ni], accO[mi2][ni], 0, 0, 0);
      }
    }
  }

  const int b = bh >> 4, head = bh & (NHEAD-1);
  u16* Obase = Opart + (size_t)sp * (M_TOT * D_MODEL);
#pragma unroll
  for (int ni = 0; ni < 2; ++ni) {
    float ls = lsum[ni];
    ls += __shfl_xor(ls, 16);
    ls += __shfl_xor(ls, 32);
    const int q = qw0 + ni*16 + l15;
    if (q4 == 0)
      Lpart[(size_t)sp*(32*N_TOK) + bh*N_TOK + q] = ls;
    const size_t rb = ((size_t)(b*N_TOK + q))*D_MODEL + head*HDIM + q4*4;
#pragma unroll
    for (int mi2 = 0; mi2 < 4; ++mi2) {
      uint2 u;
      u.x = pk2bf(accO[mi2][ni][0], accO[mi2][ni][1]);
      u.y = pk2bf(accO[mi2][ni][2], accO[mi2][ni][3]);
      *(uint2*)(Obase + rb + mi2*16) = u;
    }
  }
}

extern "C" void kernel_launch(void* const* d_in, const int* in_sizes, int n_in,
                              void* d_out, int out_size, void* d_ws, size_t ws_size,
                              hipStream_t stream) {
  const float* x  = (const float*)d_in[0];
  const float* Wq = (const float*)d_in[1];
  const float* Wk = (const float*)d_in[2];
  const float* Wv = (const float*)d_in[3];
  const float* Wo = (const float*)d_in[4];
  float* out = (float*)d_out;

  char* ws = (char*)d_ws;
  u16* xb   = (u16*)(ws);                     // 8 MB  [4096][1024]
  u16* wqt  = (u16*)(ws + (8u  << 20));       // 2 MB each, transposed [out][k]
  u16* wkt  = (u16*)(ws + (10u << 20));
  u16* wvt  = (u16*)(ws + (12u << 20));
  u16* wot  = (u16*)(ws + (14u << 20));
  u16* Qw   = (u16*)(ws + (16u << 20));       // 8 MB  [bh][n][64]  (pre-scaled)
  u16* Kw   = (u16*)(ws + (24u << 20));       // 8 MB  [bh][n][64]
  u16* Vw   = (u16*)(ws + (32u << 20));       // 8 MB  [bh][n][64]
  u16* Vtw  = (u16*)(ws + (40u << 20));       // 8 MB  [bh][64][n]
  u16* Op   = (u16*)(ws + (48u << 20));       // 16 MB [2][4096][1024] bf16
  float* Lp = (float*)(ws);                   // 512KB [2][32][2048] fp32 —
  // aliases xb: xb dead after qkv_kernel; attn writes Lp, out reads it.
  (void)in_sizes; (void)n_in; (void)out_size; (void)ws_size;

  prep_kernel<<<dim3(32, 32, 5), dim3(32, 8), 0, stream>>>(x, Wq, Wk, Wv, Wo,
                                                           xb, wqt, wkt, wvt, wot);
  qkv_kernel<<<dim3(8, 32, 3), 256, 0, stream>>>(xb, wqt, wkt, wvt, Qw, Kw, Vw);
  vtrans_kernel<<<dim3(64, 2, 32), dim3(32, 8), 0, stream>>>(Vw, Vtw);
  attn_kernel<<<dim3(32, 32), 256, 0, stream>>>(Qw, Kw, Vtw, Op, Lp);
  out_kernel<<<dim3(8, 64), 256, 0, stream>>>(Op, Lp, wot, out);
}